// Round 8
// baseline (138.876 us; speedup 1.0000x reference)
//
#include <hip/hip_runtime.h>

// BatchTopK: relu(x), keep global top (k*1024) of 1024*24576 fp32, zero rest.
// Exact radix-select on positive-fp32 bit patterns + index-ordered tie-break.
//
// R8: k_main phase-split. Phase 1 is value-free copy-shaped streaming:
// load f4 -> 4 cmp bits into a per-thread u64 -> NT-store zero. No branches,
// no atomics, ~2 live VGPRs -> compiler can pipeline 12 deep (R7's VGPR=36
// showed the branch body holding v0..v11 forced chunking). Phase 2 reloads
// only masked candidates (L3-hot) and pushes to LDS. k_scatter folded into
// k_filter (bucket>b12 keepers) + k_select (in-bucket keepers).

#define N_ELEM   25165824            // 1024 * 24576
#define NV       (N_ELEM / 4)        // float4 count = 6291456 = 2048*256*12
#define HIST_SIZE 4096               // top-12-bit buckets
#define HREP     8                   // hist replicas
#define SREP     32                  // sample blocks / private replicas
#define NS       (NV / 64)           // sampled float4 count (1/64)
#define LCAP     1024                // per-block LDS candidate buffer
#define LCAP2    1024
#define TIE_CAP  4096
#define CAND2_CAP 262144
#define CAND_CAP  16777216

typedef float f32x4 __attribute__((ext_vector_type(4)));

// ws layout (uint32 words):
#define H_OFF     0                  // 8 x 4096 main hist (counts bits >= F)
#define H2_OFF    32768              // 8 x 4096 level-2 hist (bits[19:8] in b12)
#define HS_OFF    65536              // 32 x 4096 private sample hists
#define META_OFF  196608             // 16 words
#define CAND2_OFF 196624             // cutoff-bucket candidates, uint2
#define CAND_OFF  720912             // all candidates >= F, uint2 {bits, idx}
// meta: [0]=cand cnt [1]=b12 [2]=c_above [3]=fail [4]=F [5]=keepall
//       [6]=tau [7]=cand2 cnt [8]=cand cnt snapshot (pre-fallback)

// K1 (32 blocks): zero hist+h2+meta; 1/64 sample -> private replica.
__global__ void k_sample(const float4* __restrict__ x, unsigned* __restrict__ ws) {
    __shared__ unsigned lh[HIST_SIZE];
    for (int i = threadIdx.x; i < HIST_SIZE; i += blockDim.x) lh[i] = 0u;
    int gid = blockIdx.x * blockDim.x + threadIdx.x;
    for (int i = gid; i < HS_OFF; i += SREP * 256) ws[i] = 0u;   // zero hist + h2
    if (gid < 16) ws[META_OFF + gid] = 0u;
    __syncthreads();
    for (int s = gid; s < NS; s += SREP * 256) {
        int c = s >> 6, l = s & 63;            // first 64 f4 of each 4096-f4 chunk
        float4 v = x[c * 4096 + l];
        if (v.x > 0.0f) atomicAdd(&lh[__float_as_uint(v.x) >> 20], 1u);
        if (v.y > 0.0f) atomicAdd(&lh[__float_as_uint(v.y) >> 20], 1u);
        if (v.z > 0.0f) atomicAdd(&lh[__float_as_uint(v.z) >> 20], 1u);
        if (v.w > 0.0f) atomicAdd(&lh[__float_as_uint(v.w) >> 20], 1u);
    }
    __syncthreads();
    unsigned* hs = ws + HS_OFF + blockIdx.x * HIST_SIZE;
    for (int i = threadIdx.x; i < HIST_SIZE; i += blockDim.x) hs[i] = lh[i];
}

// K2 (1 block): F = highest bucket with sampled suffix >= nk/32
// (expected full count ~2*nk; ~22-sigma safety vs nk).
__global__ void k_pick(unsigned* __restrict__ ws, const int* __restrict__ kptr) {
    __shared__ unsigned h[HIST_SIZE];
    __shared__ unsigned ps[1024];
    __shared__ unsigned F_sh;
    int t = threadIdx.x;
    if (t == 0) F_sh = 1u;
    unsigned nk = (unsigned)(*kptr) * 1024u;
    unsigned thr = nk / 32u; if (thr < 1u) thr = 1u;
    for (int i = t; i < HIST_SIZE; i += 1024) {
        unsigned s = 0u;
        #pragma unroll
        for (int r = 0; r < SREP; ++r) s += ws[HS_OFF + r * HIST_SIZE + i];
        h[i] = s;
    }
    __syncthreads();
    unsigned p = h[t*4] + h[t*4+1] + h[t*4+2] + h[t*4+3];
    ps[t] = p;
    __syncthreads();
    for (int st = 1; st < 1024; st <<= 1) {
        unsigned v = (t + st < 1024) ? ps[t + st] : 0u;
        __syncthreads();
        ps[t] += v;
        __syncthreads();
    }
    unsigned S = (t < 1023) ? ps[t + 1] : 0u;
    for (int j = 3; j >= 0; --j) {
        int b = t * 4 + j;
        unsigned Sb = S + h[b];
        if (Sb >= thr && S < thr) F_sh = ((unsigned)b) << 20;
        S = Sb;
    }
    __syncthreads();
    if (t == 0) ws[META_OFF + 4] = F_sh;
}

// K3 (2048 blocks x 256): phase-split fused pass.
__global__ __launch_bounds__(256) void k_main(const float4* __restrict__ x,
                                              float4* __restrict__ out,
                                              unsigned* __restrict__ ws,
                                              uint2* __restrict__ cand, unsigned cap) {
    __shared__ uint2 lc[LCAP];                      // 8 KB
    __shared__ unsigned lhp[HIST_SIZE / 2];         // 8 KB packed u16 pairs
    __shared__ unsigned lcnt, gbase;
    if (threadIdx.x == 0) lcnt = 0u;
    for (int i = threadIdx.x; i < HIST_SIZE / 2; i += 256) lhp[i] = 0u;
    __syncthreads();
    unsigned* meta = ws + META_OFF;
    const unsigned F = meta[4];
    unsigned* gcnt = &meta[0];
    unsigned* gh = ws + H_OFF + (blockIdx.x & (HREP - 1)) * HIST_SIZE;
    const f32x4 z = {0.f, 0.f, 0.f, 0.f};
    const int tid = blockIdx.x * 256 + threadIdx.x;
    const int stride = 2048 * 256;

    // Phase 1: copy-shaped streaming. Only live state: 48-bit mask.
    unsigned long long mask = 0ull;
    #pragma unroll
    for (int j = 0; j < 12; ++j) {
        int i = tid + j * stride;
        float4 v = x[i];
        __builtin_nontemporal_store(z, (f32x4*)&out[i]);
        unsigned m = 0u;
        m |= (__float_as_uint(fmaxf(v.x, 0.f)) >= F) ? 1u : 0u;
        m |= (__float_as_uint(fmaxf(v.y, 0.f)) >= F) ? 2u : 0u;
        m |= (__float_as_uint(fmaxf(v.z, 0.f)) >= F) ? 4u : 0u;
        m |= (__float_as_uint(fmaxf(v.w, 0.f)) >= F) ? 8u : 0u;
        mask |= ((unsigned long long)m) << (j * 4);
    }

    // Phase 2: rare reload (L2/L3-hot) + LDS push.
    if (mask) {
        const float* xf = (const float*)x;
        #pragma unroll 1
        for (int j = 0; j < 12; ++j) {
            unsigned m = (unsigned)(mask >> (j * 4)) & 0xFu;
            if (!m) continue;
            unsigned base = (unsigned)(tid + j * stride) * 4u;
            while (m) {
                unsigned c = (unsigned)__ffs(m) - 1u;
                m &= m - 1u;
                unsigned b = __float_as_uint(xf[base + c]);   // >0 guaranteed
                unsigned p = atomicAdd(&lcnt, 1u);
                if (p < LCAP) lc[p] = make_uint2(b, base + c);
                else {                                         // spill (~never)
                    unsigned q = atomicAdd(gcnt, 1u);
                    if (q < cap) { cand[q] = make_uint2(b, base + c); atomicAdd(&gh[b >> 20], 1u); }
                }
            }
        }
    }

    // Epilogue: block-local candidate histogram + single global flush.
    __syncthreads();
    unsigned n = lcnt < LCAP ? lcnt : LCAP;
    for (unsigned e = threadIdx.x; e < n; e += 256) {
        unsigned b12 = lc[e].x >> 20;
        atomicAdd(&lhp[b12 >> 1], 1u << ((b12 & 1u) * 16u));
    }
    __syncthreads();
    if (threadIdx.x == 0 && n) gbase = atomicAdd(gcnt, n);
    __syncthreads();
    for (unsigned e = threadIdx.x; e < n; e += 256) {
        unsigned q = gbase + e;
        if (q < cap) cand[q] = lc[e];
    }
    for (int i = threadIdx.x; i < HIST_SIZE / 2; i += 256) {
        unsigned w = lhp[i];
        if (w & 0xFFFFu)  atomicAdd(&gh[i * 2],     w & 0xFFFFu);
        if (w >> 16)      atomicAdd(&gh[i * 2 + 1], w >> 16);
    }
}

// K5 (guarded on fail): complement pass (0 < bits < F) appends candidates +
// histogram counts, restoring full-histogram exactness. Correctness path only.
__global__ void k_main_fb(const float4* __restrict__ x, unsigned* __restrict__ ws,
                          uint2* __restrict__ cand, unsigned cap) {
    unsigned* meta = ws + META_OFF;
    if (meta[3] == 0u) return;
    __shared__ uint2 lc[LCAP];
    __shared__ unsigned lhp[HIST_SIZE / 2];
    __shared__ unsigned lcnt, gbase;
    if (threadIdx.x == 0) lcnt = 0u;
    for (int i = threadIdx.x; i < HIST_SIZE / 2; i += blockDim.x) lhp[i] = 0u;
    __syncthreads();
    unsigned F = meta[4];
    unsigned* gcnt = &meta[0];
    unsigned* gh = ws + H_OFF + (blockIdx.x & (HREP - 1)) * HIST_SIZE;
    int stride = gridDim.x * blockDim.x;
    for (int i = blockIdx.x * blockDim.x + threadIdx.x; i < NV; i += stride) {
        float4 v = x[i];
        unsigned base = (unsigned)i * 4u;
        #pragma unroll
        for (int c = 0; c < 4; ++c) {
            float a = (c == 0) ? v.x : (c == 1) ? v.y : (c == 2) ? v.z : v.w;
            unsigned b = __float_as_uint(fmaxf(a, 0.f));
            if (b >= 1u && b < F) {
                unsigned p = atomicAdd(&lcnt, 1u);
                if (p < LCAP) lc[p] = make_uint2(b, base + c);
                else {
                    unsigned q = atomicAdd(gcnt, 1u);
                    if (q < cap) { cand[q] = make_uint2(b, base + c); atomicAdd(&gh[b >> 20], 1u); }
                }
            }
        }
    }
    __syncthreads();
    unsigned n = lcnt < LCAP ? lcnt : LCAP;
    for (unsigned e = threadIdx.x; e < n; e += blockDim.x) {
        unsigned b12 = lc[e].x >> 20;
        atomicAdd(&lhp[b12 >> 1], 1u << ((b12 & 1u) * 16u));
    }
    __syncthreads();
    if (threadIdx.x == 0 && n) gbase = atomicAdd(gcnt, n);
    __syncthreads();
    for (unsigned e = threadIdx.x; e < n; e += blockDim.x) {
        unsigned q = gbase + e;
        if (q < cap) cand[q] = lc[e];
    }
    for (int i = threadIdx.x; i < HIST_SIZE / 2; i += blockDim.x) {
        unsigned w = lhp[i];
        if (w & 0xFFFFu)  atomicAdd(&gh[i * 2],     w & 0xFFFFu);
        if (w >> 16)      atomicAdd(&gh[i * 2 + 1], w >> 16);
    }
}

// K4/K6 (1 block): suffix-scan replica-summed hist -> b12, c_above | fail | keepall.
__global__ void k_scan(unsigned* __restrict__ ws, const int* __restrict__ kptr, int is_fb) {
    unsigned* meta = ws + META_OFF;
    if (is_fb && meta[3] == 0u) return;
    __shared__ unsigned h[HIST_SIZE];
    __shared__ unsigned ps[1024];
    int t = threadIdx.x;
    unsigned nk = (unsigned)(*kptr) * 1024u;
    for (int i = t; i < HIST_SIZE; i += 1024) {
        unsigned s = 0u;
        #pragma unroll
        for (int r = 0; r < HREP; ++r) s += ws[H_OFF + r * HIST_SIZE + i];
        h[i] = s;
    }
    __syncthreads();
    unsigned p = h[t*4] + h[t*4+1] + h[t*4+2] + h[t*4+3];
    ps[t] = p;
    __syncthreads();
    for (int st = 1; st < 1024; st <<= 1) {
        unsigned v = (t + st < 1024) ? ps[t + st] : 0u;
        __syncthreads();
        ps[t] += v;
        __syncthreads();
    }
    unsigned total = ps[0];
    if (total < nk) {
        if (t == 0) {
            if (!is_fb) { meta[3] = 1u; meta[8] = meta[0]; }   // snapshot count
            else meta[5] = 1u;                                  // keep all positives
        }
        return;
    }
    unsigned S = (t < 1023) ? ps[t + 1] : 0u;
    for (int j = 3; j >= 0; --j) {
        int b = t * 4 + j;
        unsigned Sb = S + h[b];
        if (Sb >= nk && S < nk) { meta[1] = (unsigned)b; meta[2] = S; }
        S = Sb;
    }
}

// K7 (256 blocks): scatter definite keepers (bucket > b12) to out; compact
// cutoff-bucket cands -> cand2 + level-2 hist replicas. keepall: scatter all.
__global__ void k_filter(unsigned* __restrict__ ws, const uint2* __restrict__ cand,
                         uint2* __restrict__ cand2, float* __restrict__ out, unsigned cap) {
    unsigned* meta = ws + META_OFF;
    unsigned keepall = meta[5];
    unsigned ncand = meta[0]; if (ncand > cap) ncand = cap;
    unsigned stride = gridDim.x * blockDim.x;
    if (keepall) {
        for (unsigned i = blockIdx.x * blockDim.x + threadIdx.x; i < ncand; i += stride) {
            uint2 c = cand[i];
            out[c.y] = __uint_as_float(c.x);
        }
        return;
    }
    __shared__ uint2 lc[LCAP2];
    __shared__ unsigned lcnt, gbase;
    if (threadIdx.x == 0) lcnt = 0u;
    __syncthreads();
    unsigned b12 = meta[1];
    unsigned* h2 = ws + H2_OFF + (blockIdx.x & (HREP - 1)) * HIST_SIZE;
    unsigned* cnt2 = &meta[7];
    for (unsigned i = blockIdx.x * blockDim.x + threadIdx.x; i < ncand; i += stride) {
        uint2 c = cand[i];
        unsigned bk = c.x >> 20;
        if (bk > b12) {
            out[c.y] = __uint_as_float(c.x);        // definite keeper
        } else if (bk == b12) {
            atomicAdd(&h2[(c.x >> 8) & 0xFFFu], 1u);
            unsigned p = atomicAdd(&lcnt, 1u);
            if (p < LCAP2) lc[p] = c;
            else { unsigned q = atomicAdd(cnt2, 1u); if (q < CAND2_CAP) cand2[q] = c; }
        }
    }
    __syncthreads();
    unsigned n = lcnt < LCAP2 ? lcnt : LCAP2;
    if (threadIdx.x == 0 && n) gbase = atomicAdd(cnt2, n);
    __syncthreads();
    for (unsigned e = threadIdx.x; e < n; e += blockDim.x) {
        unsigned q = gbase + e;
        if (q < CAND2_CAP) cand2[q] = lc[e];
    }
}

// K8 (1 block): level-2/3 refinement -> exact tau; scatter in-bucket keepers
// (bits > tau) and the r lowest-index exact ties.
__global__ void k_select(unsigned* __restrict__ ws, const uint2* __restrict__ cand2,
                         float* __restrict__ out, const int* __restrict__ kptr) {
    unsigned* meta = ws + META_OFF;
    if (meta[5]) return;
    __shared__ unsigned h[HIST_SIZE];
    __shared__ unsigned ps[1024];
    __shared__ unsigned h3[256];
    __shared__ int ties[TIE_CAP];
    __shared__ unsigned tie_cnt;
    __shared__ unsigned s2_sh, ca2_sh, t3_sh, ca3_sh;
    int t = threadIdx.x;
    unsigned nk = (unsigned)(*kptr) * 1024u;
    unsigned b12 = meta[1];
    unsigned m = nk - meta[2];                     // rank within bucket b12, >=1
    unsigned n2 = meta[7]; if (n2 > CAND2_CAP) n2 = CAND2_CAP;
    for (int i = t; i < HIST_SIZE; i += 1024) {
        unsigned s = 0u;
        #pragma unroll
        for (int r = 0; r < HREP; ++r) s += ws[H2_OFF + r * HIST_SIZE + i];
        h[i] = s;
    }
    if (t < 256) h3[t] = 0u;
    if (t == 0) tie_cnt = 0u;
    __syncthreads();
    unsigned p = h[t*4] + h[t*4+1] + h[t*4+2] + h[t*4+3];
    ps[t] = p;
    __syncthreads();
    for (int st = 1; st < 1024; st <<= 1) {
        unsigned v = (t + st < 1024) ? ps[t + st] : 0u;
        __syncthreads();
        ps[t] += v;
        __syncthreads();
    }
    {
        unsigned S = (t < 1023) ? ps[t + 1] : 0u;
        for (int j = 3; j >= 0; --j) {
            int b = t * 4 + j;
            unsigned Sb = S + h[b];
            if (Sb >= m && S < m) { s2_sh = (unsigned)b; ca2_sh = S; }
            S = Sb;
        }
    }
    __syncthreads();
    unsigned s2 = s2_sh;
    unsigned m2 = m - ca2_sh;                      // rank within sub-bucket, >=1
    for (unsigned i = t; i < n2; i += 1024) {
        uint2 c = cand2[i];
        if (((c.x >> 8) & 0xFFFu) == s2) atomicAdd(&h3[c.x & 0xFFu], 1u);
    }
    __syncthreads();
    if (t < 256) ps[t] = h3[t];
    __syncthreads();
    for (int st = 1; st < 256; st <<= 1) {
        unsigned v = 0u;
        if (t < 256) v = (t + st < 256) ? ps[t + st] : 0u;
        __syncthreads();
        if (t < 256) ps[t] += v;
        __syncthreads();
    }
    if (t < 256) {
        unsigned S3 = (t < 255) ? ps[t + 1] : 0u;
        unsigned Sb = S3 + h3[t];
        if (Sb >= m2 && S3 < m2) { t3_sh = (unsigned)t; ca3_sh = S3; }
    }
    __syncthreads();
    unsigned tau = (b12 << 20) | (s2 << 8) | t3_sh;
    unsigned r = m2 - ca3_sh;                      // exact-tie keepers
    if (t == 0) meta[6] = tau;
    for (unsigned i = t; i < n2; i += 1024) {
        uint2 c = cand2[i];
        if (c.x > tau) {
            out[c.y] = __uint_as_float(c.x);       // in-bucket definite keeper
        } else if (c.x == tau) {
            unsigned q = atomicAdd(&tie_cnt, 1u);
            if (q < TIE_CAP) ties[q] = (int)c.y;
        }
    }
    __syncthreads();
    unsigned tc = tie_cnt; if (tc > TIE_CAP) tc = TIE_CAP;
    float tv = __uint_as_float(tau);
    for (unsigned e = t; e < tc; e += 1024) {
        int my = ties[e];
        unsigned rank = 0u;
        for (unsigned j = 0; j < tc; ++j) rank += (ties[j] < my) ? 1u : 0u;
        if (rank < r) out[my] = tv;                // keep r lowest-index ties
    }
}

extern "C" void kernel_launch(void* const* d_in, const int* in_sizes, int n_in,
                              void* d_out, int out_size, void* d_ws, size_t ws_size,
                              hipStream_t stream) {
    const float4* x = (const float4*)d_in[0];
    const int* kptr = (const int*)d_in[1];
    float* out = (float*)d_out;
    unsigned* ws32 = (unsigned*)d_ws;
    uint2* cand2 = (uint2*)(ws32 + CAND2_OFF);
    uint2* cand  = (uint2*)(ws32 + CAND_OFF);

    unsigned cap = CAND_CAP;
    size_t hdr = (size_t)CAND_OFF * 4;
    if (ws_size < hdr + (size_t)CAND_CAP * 8) {
        cap = (ws_size > hdr) ? (unsigned)((ws_size - hdr) / 8) : 0u;
    }

    k_sample<<<SREP, 256, 0, stream>>>(x, ws32);
    k_pick<<<1, 1024, 0, stream>>>(ws32, kptr);
    k_main<<<2048, 256, 0, stream>>>(x, (float4*)out, ws32, cand, cap);
    k_scan<<<1, 1024, 0, stream>>>(ws32, kptr, 0);
    k_main_fb<<<2048, 256, 0, stream>>>(x, ws32, cand, cap);    // no-op unless fail
    k_scan<<<1, 1024, 0, stream>>>(ws32, kptr, 1);              // no-op unless fail
    k_filter<<<256, 256, 0, stream>>>(ws32, cand, cand2, out, cap);
    k_select<<<1, 1024, 0, stream>>>(ws32, cand2, out, kptr);
}

// Round 9
// 136.235 us; speedup vs baseline: 1.0194x; 1.0194x over previous
//
#include <hip/hip_runtime.h>

// BatchTopK: relu(x), keep global top (k*1024) of 1024*24576 fp32, zero rest.
// Exact radix-select on positive-fp32 bit patterns + index-ordered tie-break.
//
// R9: concurrent role-split k_main. 3072 blocks in ONE launch: every 3rd
// block is a pure zero-fill block (plain stores, mirrors the 7TB/s harness
// fillBuffer); the other 2048 are pure-read + mask + rare-reload compaction.
// Tests the "per-CU stream purity" hypothesis: R4-R8 all pinned at
// 2.1-2.4TB/s with mixed per-thread streams; pure-write fill hits 7TB/s at
// 9.7% occupancy.

#define N_ELEM   25165824            // 1024 * 24576
#define NV       (N_ELEM / 4)        // float4 count = 6291456
#define HIST_SIZE 4096               // top-12-bit buckets
#define HREP     8                   // hist replicas
#define SREP     32                  // sample blocks / private replicas
#define NS       (NV / 64)           // sampled float4 count (1/64)
#define LCAP     1024                // per-block LDS candidate buffer
#define LCAP2    1024
#define TIE_CAP  4096
#define CAND2_CAP 262144
#define CAND_CAP  16777216
#define FILLB    1024                // fill blocks (1 of every 3)
#define READB    2048                // read blocks

typedef float f32x4 __attribute__((ext_vector_type(4)));

// ws layout (uint32 words):
#define H_OFF     0                  // 8 x 4096 main hist (counts bits >= F)
#define H2_OFF    32768              // 8 x 4096 level-2 hist (bits[19:8] in b12)
#define HS_OFF    65536              // 32 x 4096 private sample hists
#define META_OFF  196608             // 16 words
#define CAND2_OFF 196624             // cutoff-bucket candidates, uint2
#define CAND_OFF  720912             // all candidates >= F, uint2 {bits, idx}
// meta: [0]=cand cnt [1]=b12 [2]=c_above [3]=fail [4]=F [5]=keepall
//       [6]=tau [7]=cand2 cnt [8]=cand cnt snapshot (pre-fallback)

// K1 (32 blocks): zero hist+h2+meta; 1/64 sample -> private replica.
__global__ void k_sample(const float4* __restrict__ x, unsigned* __restrict__ ws) {
    __shared__ unsigned lh[HIST_SIZE];
    for (int i = threadIdx.x; i < HIST_SIZE; i += blockDim.x) lh[i] = 0u;
    int gid = blockIdx.x * blockDim.x + threadIdx.x;
    for (int i = gid; i < HS_OFF; i += SREP * 256) ws[i] = 0u;   // zero hist + h2
    if (gid < 16) ws[META_OFF + gid] = 0u;
    __syncthreads();
    for (int s = gid; s < NS; s += SREP * 256) {
        int c = s >> 6, l = s & 63;            // first 64 f4 of each 4096-f4 chunk
        float4 v = x[c * 4096 + l];
        if (v.x > 0.0f) atomicAdd(&lh[__float_as_uint(v.x) >> 20], 1u);
        if (v.y > 0.0f) atomicAdd(&lh[__float_as_uint(v.y) >> 20], 1u);
        if (v.z > 0.0f) atomicAdd(&lh[__float_as_uint(v.z) >> 20], 1u);
        if (v.w > 0.0f) atomicAdd(&lh[__float_as_uint(v.w) >> 20], 1u);
    }
    __syncthreads();
    unsigned* hs = ws + HS_OFF + blockIdx.x * HIST_SIZE;
    for (int i = threadIdx.x; i < HIST_SIZE; i += blockDim.x) hs[i] = lh[i];
}

// K2 (1 block): F = highest bucket with sampled suffix >= nk/32
// (expected full count ~2*nk; ~22-sigma safety vs nk).
__global__ void k_pick(unsigned* __restrict__ ws, const int* __restrict__ kptr) {
    __shared__ unsigned h[HIST_SIZE];
    __shared__ unsigned ps[1024];
    __shared__ unsigned F_sh;
    int t = threadIdx.x;
    if (t == 0) F_sh = 1u;
    unsigned nk = (unsigned)(*kptr) * 1024u;
    unsigned thr = nk / 32u; if (thr < 1u) thr = 1u;
    for (int i = t; i < HIST_SIZE; i += 1024) {
        unsigned s = 0u;
        #pragma unroll
        for (int r = 0; r < SREP; ++r) s += ws[HS_OFF + r * HIST_SIZE + i];
        h[i] = s;
    }
    __syncthreads();
    unsigned p = h[t*4] + h[t*4+1] + h[t*4+2] + h[t*4+3];
    ps[t] = p;
    __syncthreads();
    for (int st = 1; st < 1024; st <<= 1) {
        unsigned v = (t + st < 1024) ? ps[t + st] : 0u;
        __syncthreads();
        ps[t] += v;
        __syncthreads();
    }
    unsigned S = (t < 1023) ? ps[t + 1] : 0u;
    for (int j = 3; j >= 0; --j) {
        int b = t * 4 + j;
        unsigned Sb = S + h[b];
        if (Sb >= thr && S < thr) F_sh = ((unsigned)b) << 20;
        S = Sb;
    }
    __syncthreads();
    if (t == 0) ws[META_OFF + 4] = F_sh;
}

// K3 (3072 blocks x 256): role-split. blockIdx%3==0 -> pure fill (1024 blocks);
// else pure read + compact (2048 blocks).
__global__ __launch_bounds__(256) void k_main(const float4* __restrict__ x,
                                              float4* __restrict__ out,
                                              unsigned* __restrict__ ws,
                                              uint2* __restrict__ cand, unsigned cap) {
    const int b = blockIdx.x;
    if (b % 3 == 0) {
        // ---- fill role: pure plain-store zero stream (fillBuffer shape) ----
        const f32x4 z = {0.f, 0.f, 0.f, 0.f};
        int ftid = (b / 3) * 256 + threadIdx.x;
        const int fstride = FILLB * 256;
        #pragma unroll
        for (int m = 0; m < 24; ++m)
            *(f32x4*)&out[ftid + m * fstride] = z;   // 1024*256*24 == NV
        return;
    }
    // ---- read role: pure-read streaming + mask, rare reload + LDS push ----
    __shared__ uint2 lc[LCAP];                      // 8 KB
    __shared__ unsigned lhp[HIST_SIZE / 2];         // 8 KB packed u16 pairs
    __shared__ unsigned lcnt, gbase;
    if (threadIdx.x == 0) lcnt = 0u;
    for (int i = threadIdx.x; i < HIST_SIZE / 2; i += 256) lhp[i] = 0u;
    __syncthreads();
    unsigned* meta = ws + META_OFF;
    const unsigned F = meta[4];
    unsigned* gcnt = &meta[0];
    unsigned* gh = ws + H_OFF + ((unsigned)b & (HREP - 1)) * HIST_SIZE;
    const int rb = b - b / 3 - 1;                   // 0..2047
    const int tid = rb * 256 + threadIdx.x;
    const int stride = READB * 256;

    // Phase 1: pure-read. Only live state: 48-bit mask.
    unsigned long long mask = 0ull;
    #pragma unroll
    for (int j = 0; j < 12; ++j) {
        float4 v = x[tid + j * stride];
        unsigned m = 0u;
        m |= (__float_as_uint(fmaxf(v.x, 0.f)) >= F) ? 1u : 0u;
        m |= (__float_as_uint(fmaxf(v.y, 0.f)) >= F) ? 2u : 0u;
        m |= (__float_as_uint(fmaxf(v.z, 0.f)) >= F) ? 4u : 0u;
        m |= (__float_as_uint(fmaxf(v.w, 0.f)) >= F) ? 8u : 0u;
        mask |= ((unsigned long long)m) << (j * 4);
    }

    // Phase 2: rare reload (L2/L3-hot) + LDS push.
    if (mask) {
        const float* xf = (const float*)x;
        #pragma unroll 1
        for (int j = 0; j < 12; ++j) {
            unsigned m = (unsigned)(mask >> (j * 4)) & 0xFu;
            if (!m) continue;
            unsigned base = (unsigned)(tid + j * stride) * 4u;
            while (m) {
                unsigned c = (unsigned)__ffs(m) - 1u;
                m &= m - 1u;
                unsigned bb = __float_as_uint(xf[base + c]);  // >0 guaranteed
                unsigned p = atomicAdd(&lcnt, 1u);
                if (p < LCAP) lc[p] = make_uint2(bb, base + c);
                else {                                         // spill (~never)
                    unsigned q = atomicAdd(gcnt, 1u);
                    if (q < cap) { cand[q] = make_uint2(bb, base + c); atomicAdd(&gh[bb >> 20], 1u); }
                }
            }
        }
    }

    // Epilogue: block-local candidate histogram + single global flush.
    __syncthreads();
    unsigned n = lcnt < LCAP ? lcnt : LCAP;
    for (unsigned e = threadIdx.x; e < n; e += 256) {
        unsigned b12 = lc[e].x >> 20;
        atomicAdd(&lhp[b12 >> 1], 1u << ((b12 & 1u) * 16u));
    }
    __syncthreads();
    if (threadIdx.x == 0 && n) gbase = atomicAdd(gcnt, n);
    __syncthreads();
    for (unsigned e = threadIdx.x; e < n; e += 256) {
        unsigned q = gbase + e;
        if (q < cap) cand[q] = lc[e];
    }
    for (int i = threadIdx.x; i < HIST_SIZE / 2; i += 256) {
        unsigned w = lhp[i];
        if (w & 0xFFFFu)  atomicAdd(&gh[i * 2],     w & 0xFFFFu);
        if (w >> 16)      atomicAdd(&gh[i * 2 + 1], w >> 16);
    }
}

// K5 (guarded on fail): complement pass (0 < bits < F) appends candidates +
// histogram counts, restoring full-histogram exactness. Correctness path only.
__global__ void k_main_fb(const float4* __restrict__ x, unsigned* __restrict__ ws,
                          uint2* __restrict__ cand, unsigned cap) {
    unsigned* meta = ws + META_OFF;
    if (meta[3] == 0u) return;
    __shared__ uint2 lc[LCAP];
    __shared__ unsigned lhp[HIST_SIZE / 2];
    __shared__ unsigned lcnt, gbase;
    if (threadIdx.x == 0) lcnt = 0u;
    for (int i = threadIdx.x; i < HIST_SIZE / 2; i += blockDim.x) lhp[i] = 0u;
    __syncthreads();
    unsigned F = meta[4];
    unsigned* gcnt = &meta[0];
    unsigned* gh = ws + H_OFF + (blockIdx.x & (HREP - 1)) * HIST_SIZE;
    int stride = gridDim.x * blockDim.x;
    for (int i = blockIdx.x * blockDim.x + threadIdx.x; i < NV; i += stride) {
        float4 v = x[i];
        unsigned base = (unsigned)i * 4u;
        #pragma unroll
        for (int c = 0; c < 4; ++c) {
            float a = (c == 0) ? v.x : (c == 1) ? v.y : (c == 2) ? v.z : v.w;
            unsigned bb = __float_as_uint(fmaxf(a, 0.f));
            if (bb >= 1u && bb < F) {
                unsigned p = atomicAdd(&lcnt, 1u);
                if (p < LCAP) lc[p] = make_uint2(bb, base + c);
                else {
                    unsigned q = atomicAdd(gcnt, 1u);
                    if (q < cap) { cand[q] = make_uint2(bb, base + c); atomicAdd(&gh[bb >> 20], 1u); }
                }
            }
        }
    }
    __syncthreads();
    unsigned n = lcnt < LCAP ? lcnt : LCAP;
    for (unsigned e = threadIdx.x; e < n; e += blockDim.x) {
        unsigned b12 = lc[e].x >> 20;
        atomicAdd(&lhp[b12 >> 1], 1u << ((b12 & 1u) * 16u));
    }
    __syncthreads();
    if (threadIdx.x == 0 && n) gbase = atomicAdd(gcnt, n);
    __syncthreads();
    for (unsigned e = threadIdx.x; e < n; e += blockDim.x) {
        unsigned q = gbase + e;
        if (q < cap) cand[q] = lc[e];
    }
    for (int i = threadIdx.x; i < HIST_SIZE / 2; i += blockDim.x) {
        unsigned w = lhp[i];
        if (w & 0xFFFFu)  atomicAdd(&gh[i * 2],     w & 0xFFFFu);
        if (w >> 16)      atomicAdd(&gh[i * 2 + 1], w >> 16);
    }
}

// K4/K6 (1 block): suffix-scan replica-summed hist -> b12, c_above | fail | keepall.
__global__ void k_scan(unsigned* __restrict__ ws, const int* __restrict__ kptr, int is_fb) {
    unsigned* meta = ws + META_OFF;
    if (is_fb && meta[3] == 0u) return;
    __shared__ unsigned h[HIST_SIZE];
    __shared__ unsigned ps[1024];
    int t = threadIdx.x;
    unsigned nk = (unsigned)(*kptr) * 1024u;
    for (int i = t; i < HIST_SIZE; i += 1024) {
        unsigned s = 0u;
        #pragma unroll
        for (int r = 0; r < HREP; ++r) s += ws[H_OFF + r * HIST_SIZE + i];
        h[i] = s;
    }
    __syncthreads();
    unsigned p = h[t*4] + h[t*4+1] + h[t*4+2] + h[t*4+3];
    ps[t] = p;
    __syncthreads();
    for (int st = 1; st < 1024; st <<= 1) {
        unsigned v = (t + st < 1024) ? ps[t + st] : 0u;
        __syncthreads();
        ps[t] += v;
        __syncthreads();
    }
    unsigned total = ps[0];
    if (total < nk) {
        if (t == 0) {
            if (!is_fb) { meta[3] = 1u; meta[8] = meta[0]; }   // snapshot count
            else meta[5] = 1u;                                  // keep all positives
        }
        return;
    }
    unsigned S = (t < 1023) ? ps[t + 1] : 0u;
    for (int j = 3; j >= 0; --j) {
        int b = t * 4 + j;
        unsigned Sb = S + h[b];
        if (Sb >= nk && S < nk) { meta[1] = (unsigned)b; meta[2] = S; }
        S = Sb;
    }
}

// K7 (256 blocks): scatter definite keepers (bucket > b12) to out; compact
// cutoff-bucket cands -> cand2 + level-2 hist replicas. keepall: scatter all.
__global__ void k_filter(unsigned* __restrict__ ws, const uint2* __restrict__ cand,
                         uint2* __restrict__ cand2, float* __restrict__ out, unsigned cap) {
    unsigned* meta = ws + META_OFF;
    unsigned keepall = meta[5];
    unsigned ncand = meta[0]; if (ncand > cap) ncand = cap;
    unsigned stride = gridDim.x * blockDim.x;
    if (keepall) {
        for (unsigned i = blockIdx.x * blockDim.x + threadIdx.x; i < ncand; i += stride) {
            uint2 c = cand[i];
            out[c.y] = __uint_as_float(c.x);
        }
        return;
    }
    __shared__ uint2 lc[LCAP2];
    __shared__ unsigned lcnt, gbase;
    if (threadIdx.x == 0) lcnt = 0u;
    __syncthreads();
    unsigned b12 = meta[1];
    unsigned* h2 = ws + H2_OFF + (blockIdx.x & (HREP - 1)) * HIST_SIZE;
    unsigned* cnt2 = &meta[7];
    for (unsigned i = blockIdx.x * blockDim.x + threadIdx.x; i < ncand; i += stride) {
        uint2 c = cand[i];
        unsigned bk = c.x >> 20;
        if (bk > b12) {
            out[c.y] = __uint_as_float(c.x);        // definite keeper
        } else if (bk == b12) {
            atomicAdd(&h2[(c.x >> 8) & 0xFFFu], 1u);
            unsigned p = atomicAdd(&lcnt, 1u);
            if (p < LCAP2) lc[p] = c;
            else { unsigned q = atomicAdd(cnt2, 1u); if (q < CAND2_CAP) cand2[q] = c; }
        }
    }
    __syncthreads();
    unsigned n = lcnt < LCAP2 ? lcnt : LCAP2;
    if (threadIdx.x == 0 && n) gbase = atomicAdd(cnt2, n);
    __syncthreads();
    for (unsigned e = threadIdx.x; e < n; e += blockDim.x) {
        unsigned q = gbase + e;
        if (q < CAND2_CAP) cand2[q] = lc[e];
    }
}

// K8 (1 block): level-2/3 refinement -> exact tau; scatter in-bucket keepers
// (bits > tau) and the r lowest-index exact ties.
__global__ void k_select(unsigned* __restrict__ ws, const uint2* __restrict__ cand2,
                         float* __restrict__ out, const int* __restrict__ kptr) {
    unsigned* meta = ws + META_OFF;
    if (meta[5]) return;
    __shared__ unsigned h[HIST_SIZE];
    __shared__ unsigned ps[1024];
    __shared__ unsigned h3[256];
    __shared__ int ties[TIE_CAP];
    __shared__ unsigned tie_cnt;
    __shared__ unsigned s2_sh, ca2_sh, t3_sh, ca3_sh;
    int t = threadIdx.x;
    unsigned nk = (unsigned)(*kptr) * 1024u;
    unsigned b12 = meta[1];
    unsigned m = nk - meta[2];                     // rank within bucket b12, >=1
    unsigned n2 = meta[7]; if (n2 > CAND2_CAP) n2 = CAND2_CAP;
    for (int i = t; i < HIST_SIZE; i += 1024) {
        unsigned s = 0u;
        #pragma unroll
        for (int r = 0; r < HREP; ++r) s += ws[H2_OFF + r * HIST_SIZE + i];
        h[i] = s;
    }
    if (t < 256) h3[t] = 0u;
    if (t == 0) tie_cnt = 0u;
    __syncthreads();
    unsigned p = h[t*4] + h[t*4+1] + h[t*4+2] + h[t*4+3];
    ps[t] = p;
    __syncthreads();
    for (int st = 1; st < 1024; st <<= 1) {
        unsigned v = (t + st < 1024) ? ps[t + st] : 0u;
        __syncthreads();
        ps[t] += v;
        __syncthreads();
    }
    {
        unsigned S = (t < 1023) ? ps[t + 1] : 0u;
        for (int j = 3; j >= 0; --j) {
            int b = t * 4 + j;
            unsigned Sb = S + h[b];
            if (Sb >= m && S < m) { s2_sh = (unsigned)b; ca2_sh = S; }
            S = Sb;
        }
    }
    __syncthreads();
    unsigned s2 = s2_sh;
    unsigned m2 = m - ca2_sh;                      // rank within sub-bucket, >=1
    for (unsigned i = t; i < n2; i += 1024) {
        uint2 c = cand2[i];
        if (((c.x >> 8) & 0xFFFu) == s2) atomicAdd(&h3[c.x & 0xFFu], 1u);
    }
    __syncthreads();
    if (t < 256) ps[t] = h3[t];
    __syncthreads();
    for (int st = 1; st < 256; st <<= 1) {
        unsigned v = 0u;
        if (t < 256) v = (t + st < 256) ? ps[t + st] : 0u;
        __syncthreads();
        if (t < 256) ps[t] += v;
        __syncthreads();
    }
    if (t < 256) {
        unsigned S3 = (t < 255) ? ps[t + 1] : 0u;
        unsigned Sb = S3 + h3[t];
        if (Sb >= m2 && S3 < m2) { t3_sh = (unsigned)t; ca3_sh = S3; }
    }
    __syncthreads();
    unsigned tau = (b12 << 20) | (s2 << 8) | t3_sh;
    unsigned r = m2 - ca3_sh;                      // exact-tie keepers
    if (t == 0) meta[6] = tau;
    for (unsigned i = t; i < n2; i += 1024) {
        uint2 c = cand2[i];
        if (c.x > tau) {
            out[c.y] = __uint_as_float(c.x);       // in-bucket definite keeper
        } else if (c.x == tau) {
            unsigned q = atomicAdd(&tie_cnt, 1u);
            if (q < TIE_CAP) ties[q] = (int)c.y;
        }
    }
    __syncthreads();
    unsigned tc = tie_cnt; if (tc > TIE_CAP) tc = TIE_CAP;
    float tv = __uint_as_float(tau);
    for (unsigned e = t; e < tc; e += 1024) {
        int my = ties[e];
        unsigned rank = 0u;
        for (unsigned j = 0; j < tc; ++j) rank += (ties[j] < my) ? 1u : 0u;
        if (rank < r) out[my] = tv;                // keep r lowest-index ties
    }
}

extern "C" void kernel_launch(void* const* d_in, const int* in_sizes, int n_in,
                              void* d_out, int out_size, void* d_ws, size_t ws_size,
                              hipStream_t stream) {
    const float4* x = (const float4*)d_in[0];
    const int* kptr = (const int*)d_in[1];
    float* out = (float*)d_out;
    unsigned* ws32 = (unsigned*)d_ws;
    uint2* cand2 = (uint2*)(ws32 + CAND2_OFF);
    uint2* cand  = (uint2*)(ws32 + CAND_OFF);

    unsigned cap = CAND_CAP;
    size_t hdr = (size_t)CAND_OFF * 4;
    if (ws_size < hdr + (size_t)CAND_CAP * 8) {
        cap = (ws_size > hdr) ? (unsigned)((ws_size - hdr) / 8) : 0u;
    }

    k_sample<<<SREP, 256, 0, stream>>>(x, ws32);
    k_pick<<<1, 1024, 0, stream>>>(ws32, kptr);
    k_main<<<FILLB + READB, 256, 0, stream>>>(x, (float4*)out, ws32, cand, cap);
    k_scan<<<1, 1024, 0, stream>>>(ws32, kptr, 0);
    k_main_fb<<<2048, 256, 0, stream>>>(x, ws32, cand, cap);    // no-op unless fail
    k_scan<<<1, 1024, 0, stream>>>(ws32, kptr, 1);              // no-op unless fail
    k_filter<<<256, 256, 0, stream>>>(ws32, cand, cand2, out, cap);
    k_select<<<1, 1024, 0, stream>>>(ws32, cand2, out, kptr);
}

// Round 10
// 133.448 us; speedup vs baseline: 1.0407x; 1.0209x over previous
//
#include <hip/hip_runtime.h>

// BatchTopK: relu(x), keep global top (k*1024) of 1024*24576 fp32, zero rest.
// Exact radix-select on positive-fp32 bit patterns + index-ordered tie-break.
//
// R10: k_main streams x via global_load_lds (direct-to-LDS, no data VGPRs).
// R7-R9 all pinned at 2.1-2.4 TB/s because the register allocator kept only
// ~5 16B loads in flight per wave (VGPR=24-28); BW = inflight/latency =
// ~1.8KB / 375ns per CU. Staging 12x1KB per wave in LDS gives 96KB/CU in
// flight. Process from LDS (values already there -> no phase-2 reload),
// then pure NT zero-store loop.

#define N_ELEM   25165824            // 1024 * 24576
#define NV       (N_ELEM / 4)        // float4 count = 6291456 = 8192 waves * 12 * 64
#define HIST_SIZE 4096               // top-12-bit buckets
#define HREP     8                   // hist replicas
#define SREP     32                  // sample blocks / private replicas
#define NS       (NV / 64)           // sampled float4 count (1/64)
#define LCAP     512                 // per-block LDS candidate buffer
#define LCAP2    1024
#define TIE_CAP  4096
#define CAND2_CAP 262144
#define CAND_CAP  16777216

typedef float f32x4 __attribute__((ext_vector_type(4)));

// ws layout (uint32 words):
#define H_OFF     0                  // 8 x 4096 main hist (counts bits >= F)
#define H2_OFF    32768              // 8 x 4096 level-2 hist (bits[19:8] in b12)
#define HS_OFF    65536              // 32 x 4096 private sample hists
#define META_OFF  196608             // 16 words
#define CAND2_OFF 196624             // cutoff-bucket candidates, uint2
#define CAND_OFF  720912             // all candidates >= F, uint2 {bits, idx}
// meta: [0]=cand cnt [1]=b12 [2]=c_above [3]=fail [4]=F [5]=keepall
//       [6]=tau [7]=cand2 cnt [8]=cand cnt snapshot (pre-fallback)

// K1 (32 blocks): zero hist+h2+meta; 1/64 sample -> private replica.
__global__ void k_sample(const float4* __restrict__ x, unsigned* __restrict__ ws) {
    __shared__ unsigned lh[HIST_SIZE];
    for (int i = threadIdx.x; i < HIST_SIZE; i += blockDim.x) lh[i] = 0u;
    int gid = blockIdx.x * blockDim.x + threadIdx.x;
    for (int i = gid; i < HS_OFF; i += SREP * 256) ws[i] = 0u;   // zero hist + h2
    if (gid < 16) ws[META_OFF + gid] = 0u;
    __syncthreads();
    for (int s = gid; s < NS; s += SREP * 256) {
        int c = s >> 6, l = s & 63;            // first 64 f4 of each 4096-f4 chunk
        float4 v = x[c * 4096 + l];
        if (v.x > 0.0f) atomicAdd(&lh[__float_as_uint(v.x) >> 20], 1u);
        if (v.y > 0.0f) atomicAdd(&lh[__float_as_uint(v.y) >> 20], 1u);
        if (v.z > 0.0f) atomicAdd(&lh[__float_as_uint(v.z) >> 20], 1u);
        if (v.w > 0.0f) atomicAdd(&lh[__float_as_uint(v.w) >> 20], 1u);
    }
    __syncthreads();
    unsigned* hs = ws + HS_OFF + blockIdx.x * HIST_SIZE;
    for (int i = threadIdx.x; i < HIST_SIZE; i += blockDim.x) hs[i] = lh[i];
}

// K2 (1 block): F = highest bucket with sampled suffix >= nk/32
// (expected full count ~2*nk; ~22-sigma safety vs nk).
__global__ void k_pick(unsigned* __restrict__ ws, const int* __restrict__ kptr) {
    __shared__ unsigned h[HIST_SIZE];
    __shared__ unsigned ps[1024];
    __shared__ unsigned F_sh;
    int t = threadIdx.x;
    if (t == 0) F_sh = 1u;
    unsigned nk = (unsigned)(*kptr) * 1024u;
    unsigned thr = nk / 32u; if (thr < 1u) thr = 1u;
    for (int i = t; i < HIST_SIZE; i += 1024) {
        unsigned s = 0u;
        #pragma unroll
        for (int r = 0; r < SREP; ++r) s += ws[HS_OFF + r * HIST_SIZE + i];
        h[i] = s;
    }
    __syncthreads();
    unsigned p = h[t*4] + h[t*4+1] + h[t*4+2] + h[t*4+3];
    ps[t] = p;
    __syncthreads();
    for (int st = 1; st < 1024; st <<= 1) {
        unsigned v = (t + st < 1024) ? ps[t + st] : 0u;
        __syncthreads();
        ps[t] += v;
        __syncthreads();
    }
    unsigned S = (t < 1023) ? ps[t + 1] : 0u;
    for (int j = 3; j >= 0; --j) {
        int b = t * 4 + j;
        unsigned Sb = S + h[b];
        if (Sb >= thr && S < thr) F_sh = ((unsigned)b) << 20;
        S = Sb;
    }
    __syncthreads();
    if (t == 0) ws[META_OFF + 4] = F_sh;
}

// K3 (2048 blocks x 256 = 8192 waves): global_load_lds streaming pass.
// Per wave: 12 direct-to-LDS 1KB loads in flight -> vmcnt(0) -> process from
// LDS (mask + rare push, values already local) -> 12 NT zero-stores.
__global__ __launch_bounds__(256) void k_main(const float4* __restrict__ x,
                                              float4* __restrict__ out,
                                              unsigned* __restrict__ ws,
                                              uint2* __restrict__ cand, unsigned cap) {
    __shared__ float4 stage[4][12][64];             // 48 KB: 4 waves x 12 x 1KB
    __shared__ uint2 lc[LCAP];                      // 4 KB
    __shared__ unsigned lhp[HIST_SIZE / 2];         // 8 KB packed u16 pairs
    __shared__ unsigned lcnt, gbase;
    if (threadIdx.x == 0) lcnt = 0u;
    for (int i = threadIdx.x; i < HIST_SIZE / 2; i += 256) lhp[i] = 0u;
    __syncthreads();
    unsigned* meta = ws + META_OFF;
    const unsigned F = meta[4];
    unsigned* gcnt = &meta[0];
    unsigned* gh = ws + H_OFF + (blockIdx.x & (HREP - 1)) * HIST_SIZE;
    const int w = threadIdx.x >> 6;                 // wave id in block (uniform)
    const int l = threadIdx.x & 63;                 // lane
    const unsigned wid = blockIdx.x * 4u + (unsigned)w;   // 0..8191

    // Issue 12 direct-to-LDS loads (12 KB in flight per wave, no data VGPRs).
    #pragma unroll
    for (int j = 0; j < 12; ++j) {
        unsigned g = (wid + (unsigned)j * 8192u) * 64u + (unsigned)l;
        __builtin_amdgcn_global_load_lds(
            (const __attribute__((address_space(1))) void*)(x + g),
            (__attribute__((address_space(3))) void*)&stage[w][j][0],
            16, 0, 0);
    }
    asm volatile("s_waitcnt vmcnt(0)" ::: "memory");
    __builtin_amdgcn_sched_barrier(0);

    // Process from LDS: mask + rare candidate push (value already local).
    #pragma unroll
    for (int j = 0; j < 12; ++j) {
        float4 v = stage[w][j][l];
        unsigned base = ((wid + (unsigned)j * 8192u) * 64u + (unsigned)l) * 4u;
        #pragma unroll
        for (int c = 0; c < 4; ++c) {
            float a = (c == 0) ? v.x : (c == 1) ? v.y : (c == 2) ? v.z : v.w;
            unsigned b = __float_as_uint(fmaxf(a, 0.f));
            if (b >= F) {
                unsigned p = atomicAdd(&lcnt, 1u);
                if (p < LCAP) lc[p] = make_uint2(b, base + (unsigned)c);
                else {                                   // spill (~never)
                    unsigned q = atomicAdd(gcnt, 1u);
                    if (q < cap) { cand[q] = make_uint2(b, base + (unsigned)c); atomicAdd(&gh[b >> 20], 1u); }
                }
            }
        }
    }

    // Pure NT zero-store stream.
    const f32x4 z = {0.f, 0.f, 0.f, 0.f};
    #pragma unroll
    for (int j = 0; j < 12; ++j) {
        unsigned g = (wid + (unsigned)j * 8192u) * 64u + (unsigned)l;
        __builtin_nontemporal_store(z, (f32x4*)&out[g]);
    }

    // Epilogue: block-local candidate histogram + single global flush.
    __syncthreads();
    unsigned n = lcnt < LCAP ? lcnt : LCAP;
    for (unsigned e = threadIdx.x; e < n; e += 256) {
        unsigned b12 = lc[e].x >> 20;
        atomicAdd(&lhp[b12 >> 1], 1u << ((b12 & 1u) * 16u));
    }
    __syncthreads();
    if (threadIdx.x == 0 && n) gbase = atomicAdd(gcnt, n);
    __syncthreads();
    for (unsigned e = threadIdx.x; e < n; e += 256) {
        unsigned q = gbase + e;
        if (q < cap) cand[q] = lc[e];
    }
    for (int i = threadIdx.x; i < HIST_SIZE / 2; i += 256) {
        unsigned wv = lhp[i];
        if (wv & 0xFFFFu)  atomicAdd(&gh[i * 2],     wv & 0xFFFFu);
        if (wv >> 16)      atomicAdd(&gh[i * 2 + 1], wv >> 16);
    }
}

// K5 (guarded on fail): complement pass (0 < bits < F) appends candidates +
// histogram counts, restoring full-histogram exactness. Correctness path only.
__global__ void k_main_fb(const float4* __restrict__ x, unsigned* __restrict__ ws,
                          uint2* __restrict__ cand, unsigned cap) {
    unsigned* meta = ws + META_OFF;
    if (meta[3] == 0u) return;
    __shared__ uint2 lc[LCAP];
    __shared__ unsigned lhp[HIST_SIZE / 2];
    __shared__ unsigned lcnt, gbase;
    if (threadIdx.x == 0) lcnt = 0u;
    for (int i = threadIdx.x; i < HIST_SIZE / 2; i += blockDim.x) lhp[i] = 0u;
    __syncthreads();
    unsigned F = meta[4];
    unsigned* gcnt = &meta[0];
    unsigned* gh = ws + H_OFF + (blockIdx.x & (HREP - 1)) * HIST_SIZE;
    int stride = gridDim.x * blockDim.x;
    for (int i = blockIdx.x * blockDim.x + threadIdx.x; i < NV; i += stride) {
        float4 v = x[i];
        unsigned base = (unsigned)i * 4u;
        #pragma unroll
        for (int c = 0; c < 4; ++c) {
            float a = (c == 0) ? v.x : (c == 1) ? v.y : (c == 2) ? v.z : v.w;
            unsigned bb = __float_as_uint(fmaxf(a, 0.f));
            if (bb >= 1u && bb < F) {
                unsigned p = atomicAdd(&lcnt, 1u);
                if (p < LCAP) lc[p] = make_uint2(bb, base + c);
                else {
                    unsigned q = atomicAdd(gcnt, 1u);
                    if (q < cap) { cand[q] = make_uint2(bb, base + c); atomicAdd(&gh[bb >> 20], 1u); }
                }
            }
        }
    }
    __syncthreads();
    unsigned n = lcnt < LCAP ? lcnt : LCAP;
    for (unsigned e = threadIdx.x; e < n; e += blockDim.x) {
        unsigned b12 = lc[e].x >> 20;
        atomicAdd(&lhp[b12 >> 1], 1u << ((b12 & 1u) * 16u));
    }
    __syncthreads();
    if (threadIdx.x == 0 && n) gbase = atomicAdd(gcnt, n);
    __syncthreads();
    for (unsigned e = threadIdx.x; e < n; e += blockDim.x) {
        unsigned q = gbase + e;
        if (q < cap) cand[q] = lc[e];
    }
    for (int i = threadIdx.x; i < HIST_SIZE / 2; i += blockDim.x) {
        unsigned wv = lhp[i];
        if (wv & 0xFFFFu)  atomicAdd(&gh[i * 2],     wv & 0xFFFFu);
        if (wv >> 16)      atomicAdd(&gh[i * 2 + 1], wv >> 16);
    }
}

// K4/K6 (1 block): suffix-scan replica-summed hist -> b12, c_above | fail | keepall.
__global__ void k_scan(unsigned* __restrict__ ws, const int* __restrict__ kptr, int is_fb) {
    unsigned* meta = ws + META_OFF;
    if (is_fb && meta[3] == 0u) return;
    __shared__ unsigned h[HIST_SIZE];
    __shared__ unsigned ps[1024];
    int t = threadIdx.x;
    unsigned nk = (unsigned)(*kptr) * 1024u;
    for (int i = t; i < HIST_SIZE; i += 1024) {
        unsigned s = 0u;
        #pragma unroll
        for (int r = 0; r < HREP; ++r) s += ws[H_OFF + r * HIST_SIZE + i];
        h[i] = s;
    }
    __syncthreads();
    unsigned p = h[t*4] + h[t*4+1] + h[t*4+2] + h[t*4+3];
    ps[t] = p;
    __syncthreads();
    for (int st = 1; st < 1024; st <<= 1) {
        unsigned v = (t + st < 1024) ? ps[t + st] : 0u;
        __syncthreads();
        ps[t] += v;
        __syncthreads();
    }
    unsigned total = ps[0];
    if (total < nk) {
        if (t == 0) {
            if (!is_fb) { meta[3] = 1u; meta[8] = meta[0]; }   // snapshot count
            else meta[5] = 1u;                                  // keep all positives
        }
        return;
    }
    unsigned S = (t < 1023) ? ps[t + 1] : 0u;
    for (int j = 3; j >= 0; --j) {
        int b = t * 4 + j;
        unsigned Sb = S + h[b];
        if (Sb >= nk && S < nk) { meta[1] = (unsigned)b; meta[2] = S; }
        S = Sb;
    }
}

// K7 (256 blocks): scatter definite keepers (bucket > b12) to out; compact
// cutoff-bucket cands -> cand2 + level-2 hist replicas. keepall: scatter all.
__global__ void k_filter(unsigned* __restrict__ ws, const uint2* __restrict__ cand,
                         uint2* __restrict__ cand2, float* __restrict__ out, unsigned cap) {
    unsigned* meta = ws + META_OFF;
    unsigned keepall = meta[5];
    unsigned ncand = meta[0]; if (ncand > cap) ncand = cap;
    unsigned stride = gridDim.x * blockDim.x;
    if (keepall) {
        for (unsigned i = blockIdx.x * blockDim.x + threadIdx.x; i < ncand; i += stride) {
            uint2 c = cand[i];
            out[c.y] = __uint_as_float(c.x);
        }
        return;
    }
    __shared__ uint2 lc[LCAP2];
    __shared__ unsigned lcnt, gbase;
    if (threadIdx.x == 0) lcnt = 0u;
    __syncthreads();
    unsigned b12 = meta[1];
    unsigned* h2 = ws + H2_OFF + (blockIdx.x & (HREP - 1)) * HIST_SIZE;
    unsigned* cnt2 = &meta[7];
    for (unsigned i = blockIdx.x * blockDim.x + threadIdx.x; i < ncand; i += stride) {
        uint2 c = cand[i];
        unsigned bk = c.x >> 20;
        if (bk > b12) {
            out[c.y] = __uint_as_float(c.x);        // definite keeper
        } else if (bk == b12) {
            atomicAdd(&h2[(c.x >> 8) & 0xFFFu], 1u);
            unsigned p = atomicAdd(&lcnt, 1u);
            if (p < LCAP2) lc[p] = c;
            else { unsigned q = atomicAdd(cnt2, 1u); if (q < CAND2_CAP) cand2[q] = c; }
        }
    }
    __syncthreads();
    unsigned n = lcnt < LCAP2 ? lcnt : LCAP2;
    if (threadIdx.x == 0 && n) gbase = atomicAdd(cnt2, n);
    __syncthreads();
    for (unsigned e = threadIdx.x; e < n; e += blockDim.x) {
        unsigned q = gbase + e;
        if (q < CAND2_CAP) cand2[q] = lc[e];
    }
}

// K8 (1 block): level-2/3 refinement -> exact tau; scatter in-bucket keepers
// (bits > tau) and the r lowest-index exact ties.
__global__ void k_select(unsigned* __restrict__ ws, const uint2* __restrict__ cand2,
                         float* __restrict__ out, const int* __restrict__ kptr) {
    unsigned* meta = ws + META_OFF;
    if (meta[5]) return;
    __shared__ unsigned h[HIST_SIZE];
    __shared__ unsigned ps[1024];
    __shared__ unsigned h3[256];
    __shared__ int ties[TIE_CAP];
    __shared__ unsigned tie_cnt;
    __shared__ unsigned s2_sh, ca2_sh, t3_sh, ca3_sh;
    int t = threadIdx.x;
    unsigned nk = (unsigned)(*kptr) * 1024u;
    unsigned b12 = meta[1];
    unsigned m = nk - meta[2];                     // rank within bucket b12, >=1
    unsigned n2 = meta[7]; if (n2 > CAND2_CAP) n2 = CAND2_CAP;
    for (int i = t; i < HIST_SIZE; i += 1024) {
        unsigned s = 0u;
        #pragma unroll
        for (int r = 0; r < HREP; ++r) s += ws[H2_OFF + r * HIST_SIZE + i];
        h[i] = s;
    }
    if (t < 256) h3[t] = 0u;
    if (t == 0) tie_cnt = 0u;
    __syncthreads();
    unsigned p = h[t*4] + h[t*4+1] + h[t*4+2] + h[t*4+3];
    ps[t] = p;
    __syncthreads();
    for (int st = 1; st < 1024; st <<= 1) {
        unsigned v = (t + st < 1024) ? ps[t + st] : 0u;
        __syncthreads();
        ps[t] += v;
        __syncthreads();
    }
    {
        unsigned S = (t < 1023) ? ps[t + 1] : 0u;
        for (int j = 3; j >= 0; --j) {
            int b = t * 4 + j;
            unsigned Sb = S + h[b];
            if (Sb >= m && S < m) { s2_sh = (unsigned)b; ca2_sh = S; }
            S = Sb;
        }
    }
    __syncthreads();
    unsigned s2 = s2_sh;
    unsigned m2 = m - ca2_sh;                      // rank within sub-bucket, >=1
    for (unsigned i = t; i < n2; i += 1024) {
        uint2 c = cand2[i];
        if (((c.x >> 8) & 0xFFFu) == s2) atomicAdd(&h3[c.x & 0xFFu], 1u);
    }
    __syncthreads();
    if (t < 256) ps[t] = h3[t];
    __syncthreads();
    for (int st = 1; st < 256; st <<= 1) {
        unsigned v = 0u;
        if (t < 256) v = (t + st < 256) ? ps[t + st] : 0u;
        __syncthreads();
        if (t < 256) ps[t] += v;
        __syncthreads();
    }
    if (t < 256) {
        unsigned S3 = (t < 255) ? ps[t + 1] : 0u;
        unsigned Sb = S3 + h3[t];
        if (Sb >= m2 && S3 < m2) { t3_sh = (unsigned)t; ca3_sh = S3; }
    }
    __syncthreads();
    unsigned tau = (b12 << 20) | (s2 << 8) | t3_sh;
    unsigned r = m2 - ca3_sh;                      // exact-tie keepers
    if (t == 0) meta[6] = tau;
    for (unsigned i = t; i < n2; i += 1024) {
        uint2 c = cand2[i];
        if (c.x > tau) {
            out[c.y] = __uint_as_float(c.x);       // in-bucket definite keeper
        } else if (c.x == tau) {
            unsigned q = atomicAdd(&tie_cnt, 1u);
            if (q < TIE_CAP) ties[q] = (int)c.y;
        }
    }
    __syncthreads();
    unsigned tc = tie_cnt; if (tc > TIE_CAP) tc = TIE_CAP;
    float tv = __uint_as_float(tau);
    for (unsigned e = t; e < tc; e += 1024) {
        int my = ties[e];
        unsigned rank = 0u;
        for (unsigned j = 0; j < tc; ++j) rank += (ties[j] < my) ? 1u : 0u;
        if (rank < r) out[my] = tv;                // keep r lowest-index ties
    }
}

extern "C" void kernel_launch(void* const* d_in, const int* in_sizes, int n_in,
                              void* d_out, int out_size, void* d_ws, size_t ws_size,
                              hipStream_t stream) {
    const float4* x = (const float4*)d_in[0];
    const int* kptr = (const int*)d_in[1];
    float* out = (float*)d_out;
    unsigned* ws32 = (unsigned*)d_ws;
    uint2* cand2 = (uint2*)(ws32 + CAND2_OFF);
    uint2* cand  = (uint2*)(ws32 + CAND_OFF);

    unsigned cap = CAND_CAP;
    size_t hdr = (size_t)CAND_OFF * 4;
    if (ws_size < hdr + (size_t)CAND_CAP * 8) {
        cap = (ws_size > hdr) ? (unsigned)((ws_size - hdr) / 8) : 0u;
    }

    k_sample<<<SREP, 256, 0, stream>>>(x, ws32);
    k_pick<<<1, 1024, 0, stream>>>(ws32, kptr);
    k_main<<<2048, 256, 0, stream>>>(x, (float4*)out, ws32, cand, cap);
    k_scan<<<1, 1024, 0, stream>>>(ws32, kptr, 0);
    k_main_fb<<<2048, 256, 0, stream>>>(x, ws32, cand, cap);    // no-op unless fail
    k_scan<<<1, 1024, 0, stream>>>(ws32, kptr, 1);              // no-op unless fail
    k_filter<<<256, 256, 0, stream>>>(ws32, cand, cand2, out, cap);
    k_select<<<1, 1024, 0, stream>>>(ws32, cand2, out, kptr);
}